// Round 10
// baseline (382.138 us; speedup 1.0000x reference)
//
#include <hip/hip_runtime.h>
#include <stdint.h>

typedef unsigned short u16;
typedef __bf16 bf16x8 __attribute__((ext_vector_type(8)));
typedef short s16x4 __attribute__((ext_vector_type(4)));
typedef float f32x4 __attribute__((ext_vector_type(4)));

typedef __attribute__((address_space(1))) void gvoid_t;
typedef __attribute__((address_space(3))) void lvoid_t;

struct alignas(16) U128 { uint32_t x, y, z, w; };
struct alignas(16) F128 { float x, y, z, w; };
struct alignas(8)  U64v { uint32_t x, y; };

__device__ __forceinline__ void gld16(const u16* g, u16* lds) {
  __builtin_amdgcn_global_load_lds((gvoid_t*)const_cast<u16*>(g),
                                   (lvoid_t*)lds, 16, 0, 0);
}

__device__ __forceinline__ u16 f2bf(float f) {
  uint32_t u = __builtin_bit_cast(uint32_t, f);
  u += 0x7FFFu + ((u >> 16) & 1u);   // RNE
  return (u16)(u >> 16);
}
__device__ __forceinline__ float bf2f(u16 h) {
  return __builtin_bit_cast(float, (uint32_t)h << 16);
}
__device__ __forceinline__ bf16x8 ldfrag(const u16* p) {
  U128 u = *reinterpret_cast<const U128*>(p);
  return __builtin_bit_cast(bf16x8, u);
}
// pack two f32 -> bf16x2 dword, round-half-up (values >= 0)
__device__ __forceinline__ uint32_t pkbf(float a, float b) {
  uint32_t ua = __builtin_bit_cast(uint32_t, a) + 0x8000u;
  uint32_t ub = __builtin_bit_cast(uint32_t, b) + 0x8000u;
  return (ua >> 16) | (ub & 0xFFFF0000u);
}

// raw v_exp_f32 (exp2) — scores bounded (|s|<~10), no denormal concerns
__device__ __forceinline__ float EXP2(float x) { return __builtin_amdgcn_exp2f(x); }

// ---------------- fp32 -> bf16 convert (x) ----------------
__global__ void cvt_f32_bf16(const float* __restrict__ in, u16* __restrict__ out) {
  int i = (blockIdx.x * 256 + threadIdx.x) * 4;
  F128 v = *reinterpret_cast<const F128*>(in + i);
  U64v o;
  o.x = (uint32_t)f2bf(v.x) | ((uint32_t)f2bf(v.y) << 16);
  o.y = (uint32_t)f2bf(v.z) | ((uint32_t)f2bf(v.w) << 16);
  *reinterpret_cast<U64v*>(out + i) = o;
}

// ---------------- transpose + convert weights: W (K x N f32) -> Wt (N x K bf16) ----
__global__ void transpose_cvt(const float* __restrict__ W, u16* __restrict__ Wt,
                              int K, int N) {
  __shared__ float T[32][33];
  const int n0 = blockIdx.x * 32, k0 = blockIdx.y * 32;
  const int tid = threadIdx.x;
#pragma unroll
  for (int i = 0; i < 4; ++i) {
    int e = i * 256 + tid, r = e >> 5, c = e & 31;
    T[r][c] = W[(size_t)(k0 + r) * N + n0 + c];
  }
  __syncthreads();
#pragma unroll
  for (int i = 0; i < 4; ++i) {
    int e = i * 256 + tid, r = e >> 5, c = e & 31;
    Wt[(size_t)(n0 + r) * K + k0 + c] = f2bf(T[c][r]);
  }
}

// ---------------- proj GEMM: C[M,N] = A[M,K] * Bt[N,K]^T + bias (f32 out) -----------
__global__ __launch_bounds__(256, 2)
void gemm_bt(const u16* __restrict__ A, const u16* __restrict__ Bt,
             const float* __restrict__ bias, float* __restrict__ C,
             int M, int N, int K) {
  __shared__ u16 As[128 * 32];
  __shared__ u16 Bs[128 * 32];
  const int tid = threadIdx.x;
  const int wave = tid >> 6, lane = tid & 63;
  const int quad = lane >> 4, l16 = lane & 15;
  const int m0 = blockIdx.y * 128, n0 = blockIdx.x * 128;
  const int wr = (wave & 1) * 64, wc = (wave >> 1) * 64;

  f32x4 acc[4][4];
#pragma unroll
  for (int i = 0; i < 4; ++i)
#pragma unroll
    for (int j = 0; j < 4; ++j) acc[i][j] = (f32x4){0.f, 0.f, 0.f, 0.f};

  for (int k0 = 0; k0 < K; k0 += 32) {
    __syncthreads();
#pragma unroll
    for (int j = 0; j < 2; ++j) {
      int c = (wave * 2 + j) * 64 + lane;
      int row = c >> 2, kq = c & 3;
      gld16(A + (size_t)(m0 + row) * K + k0 + kq * 8, &As[(wave * 2 + j) * 512]);
      gld16(Bt + (size_t)(n0 + row) * K + k0 + kq * 8, &Bs[(wave * 2 + j) * 512]);
    }
    __syncthreads();
    bf16x8 af[4], bfr[4];
#pragma unroll
    for (int rb = 0; rb < 4; ++rb) af[rb] = ldfrag(&As[(wr + rb * 16 + l16) * 32 + quad * 8]);
#pragma unroll
    for (int cb = 0; cb < 4; ++cb) bfr[cb] = ldfrag(&Bs[(wc + cb * 16 + l16) * 32 + quad * 8]);
#pragma unroll
    for (int rb = 0; rb < 4; ++rb)
#pragma unroll
      for (int cb = 0; cb < 4; ++cb)
        acc[rb][cb] = __builtin_amdgcn_mfma_f32_16x16x32_bf16(af[rb], bfr[cb], acc[rb][cb], 0, 0, 0);
  }
#pragma unroll
  for (int cb = 0; cb < 4; ++cb) {
    int col = n0 + wc + cb * 16 + l16;
    float bv = bias[col];
#pragma unroll
    for (int rb = 0; rb < 4; ++rb) {
#pragma unroll
      for (int r = 0; r < 4; ++r) {
        int row = m0 + wr + rb * 16 + quad * 4 + r;
        C[(size_t)row * N + col] = acc[rb][cb][r] + bv;
      }
    }
  }
}

// ---------------- fused QKV GEMM + bias + RoPE + scatter ----------------------------
// blockIdx.x: 0-5 Q, 6-11 K, 12-17 V. Each wave's 64-col span == one head.
// RoPE pair (d, d+32) lives in accumulator blocks (cb, cb+2) of the SAME lane.
// Q gets D^-0.5*log2e folded in. Q,K -> (B*H, N, D); V -> (B*H, D, N) transposed.
__global__ __launch_bounds__(256, 2)
void gemm_qkv_rope(const u16* __restrict__ A, const u16* __restrict__ Bt,
                   const float* __restrict__ bias,
                   const float* __restrict__ cosT, const float* __restrict__ sinT,
                   const int* __restrict__ nsp,
                   u16* __restrict__ Qo, u16* __restrict__ Ko, u16* __restrict__ Vto) {
  __shared__ u16 As[128 * 32];
  __shared__ u16 Bs[128 * 32];
  const int K = 768, N = 2304;
  const int tid = threadIdx.x;
  const int wave = tid >> 6, lane = tid & 63;
  const int quad = lane >> 4, l16 = lane & 15;
  const int m0 = blockIdx.y * 128, n0 = blockIdx.x * 128;
  const int wr = (wave & 1) * 64, wc = (wave >> 1) * 64;

  f32x4 acc[4][4];
#pragma unroll
  for (int i = 0; i < 4; ++i)
#pragma unroll
    for (int j = 0; j < 4; ++j) acc[i][j] = (f32x4){0.f, 0.f, 0.f, 0.f};

  for (int k0 = 0; k0 < K; k0 += 32) {
    __syncthreads();
#pragma unroll
    for (int j = 0; j < 2; ++j) {
      int c = (wave * 2 + j) * 64 + lane;
      int row = c >> 2, kq = c & 3;
      gld16(A + (size_t)(m0 + row) * K + k0 + kq * 8, &As[(wave * 2 + j) * 512]);
      gld16(Bt + (size_t)(n0 + row) * K + k0 + kq * 8, &Bs[(wave * 2 + j) * 512]);
    }
    __syncthreads();
    bf16x8 af[4], bfr[4];
#pragma unroll
    for (int rb = 0; rb < 4; ++rb) af[rb] = ldfrag(&As[(wr + rb * 16 + l16) * 32 + quad * 8]);
#pragma unroll
    for (int cb = 0; cb < 4; ++cb) bfr[cb] = ldfrag(&Bs[(wc + cb * 16 + l16) * 32 + quad * 8]);
#pragma unroll
    for (int rb = 0; rb < 4; ++rb)
#pragma unroll
      for (int cb = 0; cb < 4; ++cb)
        acc[rb][cb] = __builtin_amdgcn_mfma_f32_16x16x32_bf16(af[rb], bfr[cb], acc[rb][cb], 0, 0, 0);
  }

  // ---- fused epilogue ----
  const int sec = blockIdx.x / 6;          // 0=Q, 1=K, 2=V
  const int gcol0 = n0 + wc;               // 64-aligned: one head per wave
  const int hh = (gcol0 >> 6) % 12;
  const int bb = m0 >> 11;
  const int nbase = m0 & 2047;
  const int bh = bb * 12 + hh;
  const int num_special = nsp[0];
  const float QS = 0.125f * 1.4426950408889634f;  // D^-0.5 * log2e

  if (sec < 2) {
    u16* outp = sec ? Ko : Qo;
    const float qs = sec ? 1.0f : QS;
#pragma unroll
    for (int cbp = 0; cbp < 2; ++cbp) {
      const int d1 = cbp * 16 + l16;       // 0..31
      const int d2 = d1 + 32;
      const float bv1 = bias[gcol0 + d1];
      const float bv2 = bias[gcol0 + d2];
#pragma unroll
      for (int rb = 0; rb < 4; ++rb) {
#pragma unroll
        for (int r = 0; r < 4; ++r) {
          const int n = nbase + wr + rb * 16 + quad * 4 + r;
          float v1 = acc[rb][cbp][r] + bv1;
          float v2 = acc[rb][cbp + 2][r] + bv2;
          float o1, o2;
          if (n < num_special) {
            o1 = v1; o2 = v2;
          } else {
            int ns = n - num_special;
            float c1 = cosT[ns * 64 + d1], s1 = sinT[ns * 64 + d1];
            float c2 = cosT[ns * 64 + d2], s2 = sinT[ns * 64 + d2];
            o1 = v1 * c1 - v2 * s1;
            o2 = v2 * c2 + v1 * s2;
          }
          size_t ob = ((size_t)bh * 2048 + n) * 64;
          outp[ob + d1] = f2bf(o1 * qs);
          outp[ob + d2] = f2bf(o2 * qs);
        }
      }
    }
  } else {
    // V: bias + transposed write (d-major), 4 consecutive tokens per 8B store
#pragma unroll
    for (int cb = 0; cb < 4; ++cb) {
      const int d = cb * 16 + l16;
      const float bv = bias[gcol0 + d];
#pragma unroll
      for (int rb = 0; rb < 4; ++rb) {
        const int nr = nbase + wr + rb * 16 + quad * 4;
        U64v o;
        o.x = (uint32_t)f2bf(acc[rb][cb][0] + bv) |
              ((uint32_t)f2bf(acc[rb][cb][1] + bv) << 16);
        o.y = (uint32_t)f2bf(acc[rb][cb][2] + bv) |
              ((uint32_t)f2bf(acc[rb][cb][3] + bv) << 16);
        *(U64v*)&Vto[((size_t)bh * 64 + d) * 2048 + nr] = o;
      }
    }
  }
}

// ---------------- flash attention: wave-owns-keys + register-prefetch dbuf ----------
// 1D grid 1536 = qt*48 + bh (XCD-local K/V). Wave owns 16 keys of each 64-key tile;
// Q (64x64) fully hoisted to registers. kt+1's K/V tiles are loaded into VGPRs
// during kt's compute (issued after the 2nd barrier), so the inter-barrier window
// holds only ds_writes — no exposed global latency. launch_bounds(256,3) keeps the
// VGPR cap at ~170 so the 4xU128 prefetch does NOT spill (R6's failure was the
// 85-reg cap at min-waves=6 -> 415 MB scratch; tripwire = WRITE_SIZE).
// No-max softmax (|log2-scores| < ~10) is exact in fp32.
__global__ __launch_bounds__(256, 3)
void attn(const u16* __restrict__ Q, const u16* __restrict__ Kg,
          const u16* __restrict__ Vt, u16* __restrict__ Out) {
  __shared__ u16 smem[2 * 64 * 72];   // 18432 B: [Ks | Vs]; Qs overlays Ks
  __shared__ float invS[64];
  u16* Ks = smem;
  u16* Vs = smem + 64 * 72;
  u16* Qs = smem;
  const int tid = threadIdx.x;
  const int wave = tid >> 6, lane = tid & 63;
  const int quad = lane >> 4, l16 = lane & 15;
  const int idx = blockIdx.x;
  const int bh = idx % 48, qt = idx / 48;
  const int b = bh / 12, h = bh % 12;
  const u16* Qb = Q + (size_t)bh * 2048 * 64;
  const u16* Kb = Kg + (size_t)bh * 2048 * 64;
  const u16* Vb = Vt + (size_t)bh * 64 * 2048;
  const int wkey0 = wave * 16;

  // staging geometry: chunk c = j*256+tid; row=c>>3 (0..63), kq=c&7
  const int r0 = tid >> 3, q0 = tid & 7;
  const int r1 = (256 + tid) >> 3, q1 = tid & 7;
  const u16* gk0 = Kb + r0 * 64 + q0 * 8;
  const u16* gk1 = Kb + r1 * 64 + q1 * 8;
  const u16* gv0 = Vb + (size_t)r0 * 2048 + q0 * 8;
  const u16* gv1 = Vb + (size_t)r1 * 2048 + q1 * 8;
  u16* lk0 = &Ks[r0 * 72 + q0 * 8];
  u16* lk1 = &Ks[r1 * 72 + q1 * 8];
  u16* lv0 = &Vs[r0 * 72 + q0 * 8];
  u16* lv1 = &Vs[r1 * 72 + q1 * 8];

  // stage Q tile (overlay Ks), hoist ALL Q B-frags (32 VGPRs)
  *(U128*)&Qs[r0 * 72 + q0 * 8] = *(const U128*)(Qb + (size_t)(qt * 64 + r0) * 64 + q0 * 8);
  *(U128*)&Qs[r1 * 72 + q1 * 8] = *(const U128*)(Qb + (size_t)(qt * 64 + r1) * 64 + q1 * 8);
  __syncthreads();
  bf16x8 qf[4][2];
#pragma unroll
  for (int m = 0; m < 4; ++m) {
    qf[m][0] = ldfrag(&Qs[(m * 16 + l16) * 72 + quad * 8]);
    qf[m][1] = ldfrag(&Qs[(m * 16 + l16) * 72 + quad * 8 + 32]);
  }

  // prefetch kt=0 tiles into regs
  U128 pk0 = *(const U128*)gk0, pk1 = *(const U128*)gk1;
  U128 pv0 = *(const U128*)gv0, pv1 = *(const U128*)gv1;

  f32x4 oacc[4][4];  // [q-block m][d-block db], partial over this wave's keys
#pragma unroll
  for (int m = 0; m < 4; ++m)
#pragma unroll
    for (int db = 0; db < 4; ++db) oacc[m][db] = (f32x4){0.f, 0.f, 0.f, 0.f};
  float psum[4] = {0.f, 0.f, 0.f, 0.f};

  for (int kt = 0; kt < 32; ++kt) {
    __syncthreads();               // prior-iter LDS reads (and qf reads at kt=0) done
    *(U128*)lk0 = pk0; *(U128*)lk1 = pk1;
    *(U128*)lv0 = pv0; *(U128*)lv1 = pv1;
    __syncthreads();

    // issue kt+1 loads now — latency overlaps the MFMA/exp2 section below
    if (kt < 31) {
      gk0 += 4096; gk1 += 4096; gv0 += 64; gv1 += 64;
      pk0 = *(const U128*)gk0; pk1 = *(const U128*)gk1;
      pv0 = *(const U128*)gv0; pv1 = *(const U128*)gv1;
    }

    bf16x8 ka0 = ldfrag(&Ks[(wkey0 + l16) * 72 + quad * 8]);
    bf16x8 ka1 = ldfrag(&Ks[(wkey0 + l16) * 72 + quad * 8 + 32]);

    s16x4 pf[4];
#pragma unroll
    for (int m = 0; m < 4; ++m) {
      f32x4 st = (f32x4){0.f, 0.f, 0.f, 0.f};
      st = __builtin_amdgcn_mfma_f32_16x16x32_bf16(ka0, qf[m][0], st, 0, 0, 0);
      st = __builtin_amdgcn_mfma_f32_16x16x32_bf16(ka1, qf[m][1], st, 0, 0, 0);
      float p0 = EXP2(st[0]);
      float p1 = EXP2(st[1]);
      float p2 = EXP2(st[2]);
      float p3 = EXP2(st[3]);
      psum[m] += (p0 + p1) + (p2 + p3);
      U64v pd;
      pd.x = pkbf(p0, p1);
      pd.y = pkbf(p2, p3);
      pf[m] = __builtin_bit_cast(s16x4, pd);
    }

#pragma unroll
    for (int db = 0; db < 4; ++db) {
      s16x4 vf = __builtin_bit_cast(s16x4,
          *(const U64v*)&Vs[(db * 16 + l16) * 72 + wkey0 + quad * 4]);
#pragma unroll
      for (int m = 0; m < 4; ++m)
        oacc[m][db] = __builtin_amdgcn_mfma_f32_16x16x16bf16_1k(pf[m], vf, oacc[m][db], 0, 0, 0);
    }
  }

  // ---- epilogue: cross-wave reductions ----
#pragma unroll
  for (int m = 0; m < 4; ++m) {
    psum[m] += __shfl_xor(psum[m], 16, 64);
    psum[m] += __shfl_xor(psum[m], 32, 64);
  }
  __syncthreads();
  float* LS = (float*)smem;        // [wave][64 q]
  if (quad == 0) {
#pragma unroll
    for (int m = 0; m < 4; ++m) LS[wave * 64 + m * 16 + l16] = psum[m];
  }
  __syncthreads();
  if (tid < 64) {
    float tot = LS[tid] + LS[64 + tid] + LS[128 + tid] + LS[192 + tid];
    invS[tid] = 1.0f / tot;
  }

  float* OR = (float*)smem;        // 4*64*18*4 B = 18432 B exactly
  const int q = tid >> 2;
  const int d0 = (tid & 3) * 4;
  const size_t obase = ((size_t)(b * 2048 + qt * 64 + q)) * 768 + h * 64 + d0;
#pragma unroll
  for (int db = 0; db < 4; ++db) {
    __syncthreads();
#pragma unroll
    for (int m = 0; m < 4; ++m)
#pragma unroll
      for (int r = 0; r < 4; ++r)
        OR[(wave * 64 + m * 16 + quad * 4 + r) * 18 + l16] = oacc[m][db][r];
    __syncthreads();
    float s0 = 0.f, s1 = 0.f, s2 = 0.f, s3 = 0.f;
#pragma unroll
    for (int w = 0; w < 4; ++w) {
      const float* p = &OR[(w * 64 + q) * 18 + d0];
      s0 += p[0]; s1 += p[1]; s2 += p[2]; s3 += p[3];
    }
    float iv = invS[q];
    U64v o;
    o.x = (uint32_t)f2bf(s0 * iv) | ((uint32_t)f2bf(s1 * iv) << 16);
    o.y = (uint32_t)f2bf(s2 * iv) | ((uint32_t)f2bf(s3 * iv) << 16);
    *(U64v*)&Out[obase + db * 16] = o;
  }
}

extern "C" void kernel_launch(void* const* d_in, const int* in_sizes, int n_in,
                              void* d_out, int out_size, void* d_ws, size_t ws_size,
                              hipStream_t stream) {
  (void)in_sizes; (void)n_in; (void)out_size; (void)ws_size;
  const float* x        = (const float*)d_in[0];
  const float* rope_cos = (const float*)d_in[1];
  const float* rope_sin = (const float*)d_in[2];
  const float* W_qkv    = (const float*)d_in[3];
  const float* b_qkv    = (const float*)d_in[4];
  const float* W_proj   = (const float*)d_in[5];
  const float* b_proj   = (const float*)d_in[6];
  const int*   nsp      = (const int*)d_in[7];
  float* out = (float*)d_out;

  char* ws = (char*)d_ws;
  u16* Xb   = (u16*)(ws);              // 8192x768 bf16
  u16* Wqkt = (u16*)(ws + 12582912);   // 2304x768 bf16
  u16* Wpt  = (u16*)(ws + 16121856);   // 768x768 bf16
  u16* Qb   = (u16*)(ws + 55050240);   // 48x2048x64 bf16
  u16* Kb   = (u16*)(ws + 67633152);
  u16* Vtb  = (u16*)(ws + 80216064);   // 48x64x2048 bf16
  u16* att  = (u16*)(ws + 92798976);   // 8192x768 bf16

  cvt_f32_bf16<<<6144, 256, 0, stream>>>(x, Xb);
  transpose_cvt<<<dim3(72, 24), 256, 0, stream>>>(W_qkv, Wqkt, 768, 2304);
  transpose_cvt<<<dim3(24, 24), 256, 0, stream>>>(W_proj, Wpt, 768, 768);
  gemm_qkv_rope<<<dim3(18, 64), 256, 0, stream>>>(Xb, Wqkt, b_qkv, rope_cos, rope_sin,
                                                  nsp, Qb, Kb, Vtb);
  attn<<<1536, 256, 0, stream>>>(Qb, Kb, Vtb, att);
  gemm_bt<<<dim3(6, 64), 256, 0, stream>>>(att, Wpt, b_proj, out, 8192, 768, 768);
}

// Round 11
// 251.841 us; speedup vs baseline: 1.5174x; 1.5174x over previous
//
#include <hip/hip_runtime.h>
#include <stdint.h>

typedef unsigned short u16;
typedef __bf16 bf16x8 __attribute__((ext_vector_type(8)));
typedef short s16x4 __attribute__((ext_vector_type(4)));
typedef float f32x4 __attribute__((ext_vector_type(4)));

typedef __attribute__((address_space(1))) void gvoid_t;
typedef __attribute__((address_space(3))) void lvoid_t;

struct alignas(16) U128 { uint32_t x, y, z, w; };
struct alignas(16) F128 { float x, y, z, w; };
struct alignas(8)  U64v { uint32_t x, y; };

__device__ __forceinline__ void gld16(const u16* g, u16* lds) {
  __builtin_amdgcn_global_load_lds((gvoid_t*)const_cast<u16*>(g),
                                   (lvoid_t*)lds, 16, 0, 0);
}

__device__ __forceinline__ u16 f2bf(float f) {
  uint32_t u = __builtin_bit_cast(uint32_t, f);
  u += 0x7FFFu + ((u >> 16) & 1u);   // RNE
  return (u16)(u >> 16);
}
__device__ __forceinline__ float bf2f(u16 h) {
  return __builtin_bit_cast(float, (uint32_t)h << 16);
}
__device__ __forceinline__ bf16x8 ldfrag(const u16* p) {
  U128 u = *reinterpret_cast<const U128*>(p);
  return __builtin_bit_cast(bf16x8, u);
}
// pack two f32 -> bf16x2 dword, round-half-up (values >= 0)
__device__ __forceinline__ uint32_t pkbf(float a, float b) {
  uint32_t ua = __builtin_bit_cast(uint32_t, a) + 0x8000u;
  uint32_t ub = __builtin_bit_cast(uint32_t, b) + 0x8000u;
  return (ua >> 16) | (ub & 0xFFFF0000u);
}

// raw v_exp_f32 (exp2) — scores bounded (|s|<~10), no denormal concerns
__device__ __forceinline__ float EXP2(float x) { return __builtin_amdgcn_exp2f(x); }

// ---------------- fp32 -> bf16 convert (x) ----------------
__global__ void cvt_f32_bf16(const float* __restrict__ in, u16* __restrict__ out) {
  int i = (blockIdx.x * 256 + threadIdx.x) * 4;
  F128 v = *reinterpret_cast<const F128*>(in + i);
  U64v o;
  o.x = (uint32_t)f2bf(v.x) | ((uint32_t)f2bf(v.y) << 16);
  o.y = (uint32_t)f2bf(v.z) | ((uint32_t)f2bf(v.w) << 16);
  *reinterpret_cast<U64v*>(out + i) = o;
}

// ---------------- transpose + convert weights: W (K x N f32) -> Wt (N x K bf16) ----
__global__ void transpose_cvt(const float* __restrict__ W, u16* __restrict__ Wt,
                              int K, int N) {
  __shared__ float T[32][33];
  const int n0 = blockIdx.x * 32, k0 = blockIdx.y * 32;
  const int tid = threadIdx.x;
#pragma unroll
  for (int i = 0; i < 4; ++i) {
    int e = i * 256 + tid, r = e >> 5, c = e & 31;
    T[r][c] = W[(size_t)(k0 + r) * N + n0 + c];
  }
  __syncthreads();
#pragma unroll
  for (int i = 0; i < 4; ++i) {
    int e = i * 256 + tid, r = e >> 5, c = e & 31;
    Wt[(size_t)(n0 + r) * K + k0 + c] = f2bf(T[c][r]);
  }
}

// ---------------- proj GEMM: C[M,N] = A[M,K] * Bt[N,K]^T + bias (f32 out) -----------
__global__ __launch_bounds__(256, 2)
void gemm_bt(const u16* __restrict__ A, const u16* __restrict__ Bt,
             const float* __restrict__ bias, float* __restrict__ C,
             int M, int N, int K) {
  __shared__ u16 As[128 * 32];
  __shared__ u16 Bs[128 * 32];
  const int tid = threadIdx.x;
  const int wave = tid >> 6, lane = tid & 63;
  const int quad = lane >> 4, l16 = lane & 15;
  const int m0 = blockIdx.y * 128, n0 = blockIdx.x * 128;
  const int wr = (wave & 1) * 64, wc = (wave >> 1) * 64;

  f32x4 acc[4][4];
#pragma unroll
  for (int i = 0; i < 4; ++i)
#pragma unroll
    for (int j = 0; j < 4; ++j) acc[i][j] = (f32x4){0.f, 0.f, 0.f, 0.f};

  for (int k0 = 0; k0 < K; k0 += 32) {
    __syncthreads();
#pragma unroll
    for (int j = 0; j < 2; ++j) {
      int c = (wave * 2 + j) * 64 + lane;
      int row = c >> 2, kq = c & 3;
      gld16(A + (size_t)(m0 + row) * K + k0 + kq * 8, &As[(wave * 2 + j) * 512]);
      gld16(Bt + (size_t)(n0 + row) * K + k0 + kq * 8, &Bs[(wave * 2 + j) * 512]);
    }
    __syncthreads();
    bf16x8 af[4], bfr[4];
#pragma unroll
    for (int rb = 0; rb < 4; ++rb) af[rb] = ldfrag(&As[(wr + rb * 16 + l16) * 32 + quad * 8]);
#pragma unroll
    for (int cb = 0; cb < 4; ++cb) bfr[cb] = ldfrag(&Bs[(wc + cb * 16 + l16) * 32 + quad * 8]);
#pragma unroll
    for (int rb = 0; rb < 4; ++rb)
#pragma unroll
      for (int cb = 0; cb < 4; ++cb)
        acc[rb][cb] = __builtin_amdgcn_mfma_f32_16x16x32_bf16(af[rb], bfr[cb], acc[rb][cb], 0, 0, 0);
  }
#pragma unroll
  for (int cb = 0; cb < 4; ++cb) {
    int col = n0 + wc + cb * 16 + l16;
    float bv = bias[col];
#pragma unroll
    for (int rb = 0; rb < 4; ++rb) {
#pragma unroll
      for (int r = 0; r < 4; ++r) {
        int row = m0 + wr + rb * 16 + quad * 4 + r;
        C[(size_t)row * N + col] = acc[rb][cb][r] + bv;
      }
    }
  }
}

// ---------------- fused QKV GEMM + bias + RoPE + scatter ----------------------------
// blockIdx.x: 0-5 Q, 6-11 K, 12-17 V. Each wave's 64-col span == one head.
// RoPE pair (d, d+32) lives in accumulator blocks (cb, cb+2) of the SAME lane.
// Q gets D^-0.5*log2e folded in. Q,K -> (B*H, N, D); V -> (B*H, D, N) transposed.
__global__ __launch_bounds__(256, 2)
void gemm_qkv_rope(const u16* __restrict__ A, const u16* __restrict__ Bt,
                   const float* __restrict__ bias,
                   const float* __restrict__ cosT, const float* __restrict__ sinT,
                   const int* __restrict__ nsp,
                   u16* __restrict__ Qo, u16* __restrict__ Ko, u16* __restrict__ Vto) {
  __shared__ u16 As[128 * 32];
  __shared__ u16 Bs[128 * 32];
  const int K = 768, N = 2304;
  const int tid = threadIdx.x;
  const int wave = tid >> 6, lane = tid & 63;
  const int quad = lane >> 4, l16 = lane & 15;
  const int m0 = blockIdx.y * 128, n0 = blockIdx.x * 128;
  const int wr = (wave & 1) * 64, wc = (wave >> 1) * 64;

  f32x4 acc[4][4];
#pragma unroll
  for (int i = 0; i < 4; ++i)
#pragma unroll
    for (int j = 0; j < 4; ++j) acc[i][j] = (f32x4){0.f, 0.f, 0.f, 0.f};

  for (int k0 = 0; k0 < K; k0 += 32) {
    __syncthreads();
#pragma unroll
    for (int j = 0; j < 2; ++j) {
      int c = (wave * 2 + j) * 64 + lane;
      int row = c >> 2, kq = c & 3;
      gld16(A + (size_t)(m0 + row) * K + k0 + kq * 8, &As[(wave * 2 + j) * 512]);
      gld16(Bt + (size_t)(n0 + row) * K + k0 + kq * 8, &Bs[(wave * 2 + j) * 512]);
    }
    __syncthreads();
    bf16x8 af[4], bfr[4];
#pragma unroll
    for (int rb = 0; rb < 4; ++rb) af[rb] = ldfrag(&As[(wr + rb * 16 + l16) * 32 + quad * 8]);
#pragma unroll
    for (int cb = 0; cb < 4; ++cb) bfr[cb] = ldfrag(&Bs[(wc + cb * 16 + l16) * 32 + quad * 8]);
#pragma unroll
    for (int rb = 0; rb < 4; ++rb)
#pragma unroll
      for (int cb = 0; cb < 4; ++cb)
        acc[rb][cb] = __builtin_amdgcn_mfma_f32_16x16x32_bf16(af[rb], bfr[cb], acc[rb][cb], 0, 0, 0);
  }

  // ---- fused epilogue ----
  const int sec = blockIdx.x / 6;          // 0=Q, 1=K, 2=V
  const int gcol0 = n0 + wc;               // 64-aligned: one head per wave
  const int hh = (gcol0 >> 6) % 12;
  const int bb = m0 >> 11;
  const int nbase = m0 & 2047;
  const int bh = bb * 12 + hh;
  const int num_special = nsp[0];
  const float QS = 0.125f * 1.4426950408889634f;  // D^-0.5 * log2e

  if (sec < 2) {
    u16* outp = sec ? Ko : Qo;
    const float qs = sec ? 1.0f : QS;
#pragma unroll
    for (int cbp = 0; cbp < 2; ++cbp) {
      const int d1 = cbp * 16 + l16;       // 0..31
      const int d2 = d1 + 32;
      const float bv1 = bias[gcol0 + d1];
      const float bv2 = bias[gcol0 + d2];
#pragma unroll
      for (int rb = 0; rb < 4; ++rb) {
#pragma unroll
        for (int r = 0; r < 4; ++r) {
          const int n = nbase + wr + rb * 16 + quad * 4 + r;
          float v1 = acc[rb][cbp][r] + bv1;
          float v2 = acc[rb][cbp + 2][r] + bv2;
          float o1, o2;
          if (n < num_special) {
            o1 = v1; o2 = v2;
          } else {
            int ns = n - num_special;
            float c1 = cosT[ns * 64 + d1], s1 = sinT[ns * 64 + d1];
            float c2 = cosT[ns * 64 + d2], s2 = sinT[ns * 64 + d2];
            o1 = v1 * c1 - v2 * s1;
            o2 = v2 * c2 + v1 * s2;
          }
          size_t ob = ((size_t)bh * 2048 + n) * 64;
          outp[ob + d1] = f2bf(o1 * qs);
          outp[ob + d2] = f2bf(o2 * qs);
        }
      }
    }
  } else {
    // V: bias + transposed write (d-major), 4 consecutive tokens per 8B store
#pragma unroll
    for (int cb = 0; cb < 4; ++cb) {
      const int d = cb * 16 + l16;
      const float bv = bias[gcol0 + d];
#pragma unroll
      for (int rb = 0; rb < 4; ++rb) {
        const int nr = nbase + wr + rb * 16 + quad * 4;
        U64v o;
        o.x = (uint32_t)f2bf(acc[rb][cb][0] + bv) |
              ((uint32_t)f2bf(acc[rb][cb][1] + bv) << 16);
        o.y = (uint32_t)f2bf(acc[rb][cb][2] + bv) |
              ((uint32_t)f2bf(acc[rb][cb][3] + bv) << 16);
        *(U64v*)&Vto[((size_t)bh * 64 + d) * 2048 + nr] = o;
      }
    }
  }
}

// ---------------- flash attention: async double-buffered gld16 pipeline -------------
// 1D grid 1536 = qt*48 + bh (XCD-local K/V). Wave owns 16 keys of each 64-key tile;
// Q (64x64) fully hoisted to registers. Staging uses global_load_lds (fire-and-
// forget, ZERO VGPR live range — the R6/R10 spill trap is structurally impossible).
// LDS is unpadded (64-u16 rows) as gld16 requires; bank conflicts on frag reads are
// avoided with an XOR swizzle: physical chunk p of row r holds logical chunk
// p^(r&7); readers address logical^(row&7). One barrier per kt: barrier (drains
// tile-kt loads via implicit vmcnt(0)) -> issue tile-(kt+1) loads into the other
// buffer -> compute tile kt. No-max softmax (|log2-scores| < ~10) exact in fp32.
__global__ __launch_bounds__(256, 3)
void attn(const u16* __restrict__ Q, const u16* __restrict__ Kg,
          const u16* __restrict__ Vt, u16* __restrict__ Out) {
  __shared__ u16 smem[4 * 4096];   // 32768 B: K0 | V0 | K1 | V1 (4096 u16 each)
  __shared__ float invS[64];
  u16* K0 = smem;
  u16* V0 = smem + 4096;
  u16* K1 = smem + 8192;
  u16* V1 = smem + 12288;
  const int tid = threadIdx.x;
  const int wave = tid >> 6, lane = tid & 63;
  const int quad = lane >> 4, l16 = lane & 15;
  const int idx = blockIdx.x;
  const int bh = idx % 48, qt = idx / 48;
  const int b = bh / 12, h = bh % 12;
  const u16* Qb = Q + (size_t)bh * 2048 * 64;
  const u16* Kb = Kg + (size_t)bh * 2048 * 64;
  const u16* Vb = Vt + (size_t)bh * 64 * 2048;
  const int wkey0 = wave * 16;

  // staging: chunk p = wave*128 + i*64 + lane; row = p>>3, phys chunk = p&7,
  // source logical chunk = (p&7) ^ (row&7)
  const int srow = lane >> 3;             // 0..7 (== row&7 for both i)
  const int scol = (lane & 7) ^ srow;     // swizzled source chunk
  const int row0 = wave * 16 + srow;
  const int row1 = wave * 16 + 8 + srow;
  const int dst0 = wave * 1024;           // u16 LDS offset (wave-uniform)
  const int dst1 = wave * 1024 + 512;

  // stage Q -> K1 region, tile 0 -> buf0 (all async)
  gld16(Qb + (size_t)(qt * 64 + row0) * 64 + scol * 8, K1 + dst0);
  gld16(Qb + (size_t)(qt * 64 + row1) * 64 + scol * 8, K1 + dst1);
  gld16(Kb + row0 * 64 + scol * 8, K0 + dst0);
  gld16(Kb + row1 * 64 + scol * 8, K0 + dst1);
  gld16(Vb + (size_t)row0 * 2048 + scol * 8, V0 + dst0);
  gld16(Vb + (size_t)row1 * 2048 + scol * 8, V0 + dst1);
  __syncthreads();   // implicit vmcnt(0) drain: Q + tile0 resident

  const int r7 = l16 & 7;
  const int kc = quad ^ r7;               // physical chunk of logical chunk `quad`
  bf16x8 qf[4][2];
#pragma unroll
  for (int m = 0; m < 4; ++m) {
    const u16* qrow = &K1[(m * 16 + l16) * 64];
    qf[m][0] = ldfrag(qrow + kc * 8);
    qf[m][1] = ldfrag(qrow + (kc ^ 4) * 8);
  }

  f32x4 oacc[4][4];  // [q-block m][d-block db], partial over this wave's keys
#pragma unroll
  for (int m = 0; m < 4; ++m)
#pragma unroll
    for (int db = 0; db < 4; ++db) oacc[m][db] = (f32x4){0.f, 0.f, 0.f, 0.f};
  float psum[4] = {0.f, 0.f, 0.f, 0.f};

  const int vchunk = wave * 2 + (quad >> 1);   // logical V chunk for this lane
  const int voff = (quad & 1) * 4;             // u16 offset within chunk

  for (int kt = 0; kt < 32; ++kt) {
    __syncthreads();   // drains tile-kt loads (all waves); frees other buffer
    const u16* cK = (kt & 1) ? K1 : K0;
    const u16* cV = (kt & 1) ? V1 : V0;
    if (kt < 31) {     // issue tile kt+1 into the other buffer; overlaps compute
      u16* nK = (kt & 1) ? K0 : K1;
      u16* nV = (kt & 1) ? V0 : V1;
      const int nk = kt + 1;
      gld16(Kb + nk * 4096 + row0 * 64 + scol * 8, nK + dst0);
      gld16(Kb + nk * 4096 + row1 * 64 + scol * 8, nK + dst1);
      gld16(Vb + (size_t)row0 * 2048 + nk * 64 + scol * 8, nV + dst0);
      gld16(Vb + (size_t)row1 * 2048 + nk * 64 + scol * 8, nV + dst1);
    }

    const u16* krow = &cK[(wkey0 + l16) * 64];
    bf16x8 ka0 = ldfrag(krow + kc * 8);
    bf16x8 ka1 = ldfrag(krow + (kc ^ 4) * 8);

    s16x4 pf[4];
#pragma unroll
    for (int m = 0; m < 4; ++m) {
      f32x4 st = (f32x4){0.f, 0.f, 0.f, 0.f};
      st = __builtin_amdgcn_mfma_f32_16x16x32_bf16(ka0, qf[m][0], st, 0, 0, 0);
      st = __builtin_amdgcn_mfma_f32_16x16x32_bf16(ka1, qf[m][1], st, 0, 0, 0);
      float p0 = EXP2(st[0]);
      float p1 = EXP2(st[1]);
      float p2 = EXP2(st[2]);
      float p3 = EXP2(st[3]);
      psum[m] += (p0 + p1) + (p2 + p3);
      U64v pd;
      pd.x = pkbf(p0, p1);
      pd.y = pkbf(p2, p3);
      pf[m] = __builtin_bit_cast(s16x4, pd);
    }

#pragma unroll
    for (int db = 0; db < 4; ++db) {
      const int vrow = db * 16 + l16;          // vrow&7 == r7
      s16x4 vf = __builtin_bit_cast(s16x4,
          *(const U64v*)&cV[vrow * 64 + (vchunk ^ r7) * 8 + voff]);
#pragma unroll
      for (int m = 0; m < 4; ++m)
        oacc[m][db] = __builtin_amdgcn_mfma_f32_16x16x16bf16_1k(pf[m], vf, oacc[m][db], 0, 0, 0);
    }
  }

  // ---- epilogue: cross-wave reductions ----
#pragma unroll
  for (int m = 0; m < 4; ++m) {
    psum[m] += __shfl_xor(psum[m], 16, 64);
    psum[m] += __shfl_xor(psum[m], 32, 64);
  }
  __syncthreads();
  float* LS = (float*)smem;        // [wave][64 q]
  if (quad == 0) {
#pragma unroll
    for (int m = 0; m < 4; ++m) LS[wave * 64 + m * 16 + l16] = psum[m];
  }
  __syncthreads();
  if (tid < 64) {
    float tot = LS[tid] + LS[64 + tid] + LS[128 + tid] + LS[192 + tid];
    invS[tid] = 1.0f / tot;
  }

  float* OR = (float*)smem;        // 4*64*18*4 B = 18432 B (fits in 32768)
  const int q = tid >> 2;
  const int d0 = (tid & 3) * 4;
  const size_t obase = ((size_t)(b * 2048 + qt * 64 + q)) * 768 + h * 64 + d0;
#pragma unroll
  for (int db = 0; db < 4; ++db) {
    __syncthreads();
#pragma unroll
    for (int m = 0; m < 4; ++m)
#pragma unroll
      for (int r = 0; r < 4; ++r)
        OR[(wave * 64 + m * 16 + quad * 4 + r) * 18 + l16] = oacc[m][db][r];
    __syncthreads();
    float s0 = 0.f, s1 = 0.f, s2 = 0.f, s3 = 0.f;
#pragma unroll
    for (int w = 0; w < 4; ++w) {
      const float* p = &OR[(w * 64 + q) * 18 + d0];
      s0 += p[0]; s1 += p[1]; s2 += p[2]; s3 += p[3];
    }
    float iv = invS[q];
    U64v o;
    o.x = (uint32_t)f2bf(s0 * iv) | ((uint32_t)f2bf(s1 * iv) << 16);
    o.y = (uint32_t)f2bf(s2 * iv) | ((uint32_t)f2bf(s3 * iv) << 16);
    *(U64v*)&Out[obase + db * 16] = o;
  }
}

extern "C" void kernel_launch(void* const* d_in, const int* in_sizes, int n_in,
                              void* d_out, int out_size, void* d_ws, size_t ws_size,
                              hipStream_t stream) {
  (void)in_sizes; (void)n_in; (void)out_size; (void)ws_size;
  const float* x        = (const float*)d_in[0];
  const float* rope_cos = (const float*)d_in[1];
  const float* rope_sin = (const float*)d_in[2];
  const float* W_qkv    = (const float*)d_in[3];
  const float* b_qkv    = (const float*)d_in[4];
  const float* W_proj   = (const float*)d_in[5];
  const float* b_proj   = (const float*)d_in[6];
  const int*   nsp      = (const int*)d_in[7];
  float* out = (float*)d_out;

  char* ws = (char*)d_ws;
  u16* Xb   = (u16*)(ws);              // 8192x768 bf16
  u16* Wqkt = (u16*)(ws + 12582912);   // 2304x768 bf16
  u16* Wpt  = (u16*)(ws + 16121856);   // 768x768 bf16
  u16* Qb   = (u16*)(ws + 55050240);   // 48x2048x64 bf16
  u16* Kb   = (u16*)(ws + 67633152);
  u16* Vtb  = (u16*)(ws + 80216064);   // 48x64x2048 bf16
  u16* att  = (u16*)(ws + 92798976);   // 8192x768 bf16

  cvt_f32_bf16<<<6144, 256, 0, stream>>>(x, Xb);
  transpose_cvt<<<dim3(72, 24), 256, 0, stream>>>(W_qkv, Wqkt, 768, 2304);
  transpose_cvt<<<dim3(24, 24), 256, 0, stream>>>(W_proj, Wpt, 768, 768);
  gemm_qkv_rope<<<dim3(18, 64), 256, 0, stream>>>(Xb, Wqkt, b_qkv, rope_cos, rope_sin,
                                                  nsp, Qb, Kb, Vtb);
  attn<<<1536, 256, 0, stream>>>(Qb, Kb, Vtb, att);
  gemm_bt<<<dim3(6, 64), 256, 0, stream>>>(att, Wpt, b_proj, out, 8192, 768, 768);
}